// Round 1
// baseline (585.753 us; speedup 1.0000x reference)
//
#include <hip/hip_runtime.h>

// ---------------------------------------------------------------------------
// Problem constants
//   B=8, S=4096, D=1024, DS=64
//   segments: qk 512 | v 256 | rel 128 | val 64  (know 256 unused)
//   outputs (flat fp32): idx_qk 8x64 | idx_v 8x32 | rel_Q 8x128 | rel_K 8x128 | val_w 8x64
// ---------------------------------------------------------------------------

// ---- k_norm: embT[kk][n] = emb[n][kk]/||emb[n]||  (n<960), and zero wg ----
__global__ __launch_bounds__(256) void k_norm(const float* __restrict__ emb,
                                              float* __restrict__ embT,
                                              float* __restrict__ wg) {
  int tid = threadIdx.x;
  int gid = blockIdx.x * 256 + tid;
  if (gid < 8 * 960) wg[gid] = 0.f;
  int wave = tid >> 6, lane = tid & 63;
  int n = blockIdx.x * 4 + wave;
  if (n < 960) {
    float v = emb[n * 64 + lane];
    float s = v * v;
#pragma unroll
    for (int off = 1; off < 64; off <<= 1) s += __shfl_xor(s, off);
    float inv = 1.0f / sqrtf(s);
    embT[lane * 960 + n] = v * inv;
  }
}

// ---- k_proj: h[32768][64] = x[32768][1024] @ w[64][1024]^T + b ----
__global__ __launch_bounds__(256) void k_proj(const float* __restrict__ x,
                                              const float* __restrict__ w,
                                              const float* __restrict__ bvec,
                                              float* __restrict__ h) {
  __shared__ __align__(16) float xT[32][68];  // [kk][m], pad 68 to spread staging banks
  __shared__ __align__(16) float wT[32][68];  // [kk][k]
  int tid = threadIdx.x;
  int tx = tid & 15, ty = tid >> 4;
  int m0 = blockIdx.x * 64;
  float acc[4][4];
#pragma unroll
  for (int i = 0; i < 4; ++i)
#pragma unroll
    for (int j = 0; j < 4; ++j) acc[i][j] = 0.f;

  for (int kc = 0; kc < 1024; kc += 32) {
    __syncthreads();
#pragma unroll
    for (int p = 0; p < 2; ++p) {
      int fi = tid + p * 256;
      int r = fi >> 3, cq = fi & 7;  // r: 0..63 row, cq: 0..7 k-quad
      float4 v = *(const float4*)&x[(size_t)(m0 + r) * 1024 + kc + 4 * cq];
      xT[4 * cq + 0][r] = v.x; xT[4 * cq + 1][r] = v.y;
      xT[4 * cq + 2][r] = v.z; xT[4 * cq + 3][r] = v.w;
      float4 u = *(const float4*)&w[(size_t)r * 1024 + kc + 4 * cq];
      wT[4 * cq + 0][r] = u.x; wT[4 * cq + 1][r] = u.y;
      wT[4 * cq + 2][r] = u.z; wT[4 * cq + 3][r] = u.w;
    }
    __syncthreads();
#pragma unroll
    for (int kk = 0; kk < 32; ++kk) {
      float4 a4 = *(const float4*)&xT[kk][4 * ty];
      float4 b4 = *(const float4*)&wT[kk][4 * tx];
      float av[4] = {a4.x, a4.y, a4.z, a4.w};
      float bv[4] = {b4.x, b4.y, b4.z, b4.w};
#pragma unroll
      for (int i = 0; i < 4; ++i)
#pragma unroll
        for (int j = 0; j < 4; ++j) acc[i][j] = fmaf(av[i], bv[j], acc[i][j]);
    }
  }
  float4 bias4 = *(const float4*)&bvec[4 * tx];
  float bb[4] = {bias4.x, bias4.y, bias4.z, bias4.w};
#pragma unroll
  for (int i = 0; i < 4; ++i) {
    float4 o;
    o.x = acc[i][0] + bb[0]; o.y = acc[i][1] + bb[1];
    o.z = acc[i][2] + bb[2]; o.w = acc[i][3] + bb[3];
    *(float4*)&h[(size_t)(m0 + 4 * ty + i) * 64 + 4 * tx] = o;
  }
}

// ---- k_agg: fused logits(960) + per-segment softmax + importance-weighted agg ----
// block = 32 rows (one b), wave = 8 rows; lanes own neurons; acc/softmax in regs.
template <int SOFF, int SN>
__device__ __forceinline__ void process_seg(const float* __restrict__ embT,
                                            const float (&hs)[32][64],
                                            float* __restrict__ embc,
                                            float (*wpart)[960],
                                            const float (&impr)[8],
                                            int wr0, int wave, int lane, int tid) {
  constexpr int P = SN / 64;  // neurons per lane in this segment
  float acc[P][8];
#pragma unroll
  for (int p = 0; p < P; ++p)
#pragma unroll
    for (int r = 0; r < 8; ++r) acc[p][r] = 0.f;

  if constexpr (SN >= 128) {
    constexpr int NCH = SN / 128;
#pragma unroll
    for (int c = 0; c < NCH; ++c) {
      __syncthreads();
#pragma unroll
      for (int p = 0; p < 8; ++p) {  // stage embc[kk][0..127] (32 KiB)
        int fi = tid + p * 256;
        int kk = fi >> 5, cq = fi & 31;
        *(float4*)&embc[kk * 128 + 4 * cq] =
            *(const float4*)&embT[(size_t)kk * 960 + SOFF + c * 128 + 4 * cq];
      }
      __syncthreads();
      for (int kkq = 0; kkq < 16; ++kkq) {
        float4 hq[8];
#pragma unroll
        for (int r = 0; r < 8; ++r) hq[r] = *(const float4*)&hs[wr0 + r][4 * kkq];
#pragma unroll
        for (int i = 0; i < 4; ++i) {
          float2 e = *(const float2*)&embc[(4 * kkq + i) * 128 + 2 * lane];
#pragma unroll
          for (int r = 0; r < 8; ++r) {
            float hv = ((const float*)&hq[r])[i];
            acc[2 * c + 0][r] = fmaf(e.x, hv, acc[2 * c + 0][r]);
            acc[2 * c + 1][r] = fmaf(e.y, hv, acc[2 * c + 1][r]);
          }
        }
      }
    }
  } else {  // SN == 64
    __syncthreads();
#pragma unroll
    for (int p = 0; p < 4; ++p) {
      int fi = tid + p * 256;
      int kk = fi >> 4, cq = fi & 15;
      *(float4*)&embc[kk * 64 + 4 * cq] =
          *(const float4*)&embT[(size_t)kk * 960 + SOFF + 4 * cq];
    }
    __syncthreads();
    for (int kkq = 0; kkq < 16; ++kkq) {
      float4 hq[8];
#pragma unroll
      for (int r = 0; r < 8; ++r) hq[r] = *(const float4*)&hs[wr0 + r][4 * kkq];
#pragma unroll
      for (int i = 0; i < 4; ++i) {
        float e = embc[(4 * kkq + i) * 64 + lane];
#pragma unroll
        for (int r = 0; r < 8; ++r) {
          float hv = ((const float*)&hq[r])[i];
          acc[0][r] = fmaf(e, hv, acc[0][r]);
        }
      }
    }
  }

  // segment softmax (per row) + contribution = sum_r (imp_r / sum_r) * exp(logit)
  float coef[8];
#pragma unroll
  for (int r = 0; r < 8; ++r) {
    float s = 0.f;
#pragma unroll
    for (int p = 0; p < P; ++p) {
      float e = __expf(acc[p][r]);
      acc[p][r] = e;
      s += e;
    }
#pragma unroll
    for (int off = 1; off < 64; off <<= 1) s += __shfl_xor(s, off);
    coef[r] = impr[r] / s;
  }
#pragma unroll
  for (int p = 0; p < P; ++p) {
    float contrib = 0.f;
#pragma unroll
    for (int r = 0; r < 8; ++r) contrib = fmaf(acc[p][r], coef[r], contrib);
    int nloc = (P == 1) ? lane : ((p >> 1) * 128 + 2 * lane + (p & 1));
    wpart[wave][SOFF + nloc] = contrib;
  }
}

__global__ __launch_bounds__(256) void k_agg(const float* __restrict__ h,
                                             const float* __restrict__ embT,
                                             const float* __restrict__ imp,
                                             float* __restrict__ wg) {
  __shared__ __align__(16) float hs[32][64];
  __shared__ __align__(16) float embc[64 * 128];
  __shared__ float wpart[4][960];
  int tid = threadIdx.x, wave = tid >> 6, lane = tid & 63;
  int row0 = blockIdx.x * 32;
  int b = row0 >> 12;  // 4096 rows per batch
#pragma unroll
  for (int p = 0; p < 2; ++p) {
    int fi = tid + p * 256;
    int r = fi >> 4, cq = fi & 15;
    *(float4*)&hs[r][4 * cq] = *(const float4*)&h[(size_t)(row0 + r) * 64 + 4 * cq];
  }
  int wr0 = wave * 8;
  float impr[8];
#pragma unroll
  for (int r = 0; r < 8; ++r) impr[r] = imp[row0 + wr0 + r];
  // hs visibility guaranteed by the first barrier inside process_seg

  process_seg<0, 512>(embT, hs, embc, wpart, impr, wr0, wave, lane, tid);
  process_seg<512, 256>(embT, hs, embc, wpart, impr, wr0, wave, lane, tid);
  process_seg<768, 128>(embT, hs, embc, wpart, impr, wr0, wave, lane, tid);
  process_seg<896, 64>(embT, hs, embc, wpart, impr, wr0, wave, lane, tid);

  __syncthreads();
  for (int n = tid; n < 960; n += 256) {
    float s = wpart[0][n] + wpart[1][n] + wpart[2][n] + wpart[3][n];
    atomicAdd(&wg[b * 960 + n], s);
  }
}

// ---- k_topk: per (b, type) iterative top-k extraction + output emission ----
__global__ __launch_bounds__(64) void k_topk(const float* __restrict__ wg,
                                             float* __restrict__ out) {
  __shared__ float vals[512];
  __shared__ int flags[512];
  int blk = blockIdx.x;
  int b = blk >> 2, t = blk & 3;
  int lane = threadIdx.x;
  const int Ns[4] = {512, 256, 128, 64};
  const int Ks[4] = {64, 32, 16, 3};
  const int Off[4] = {0, 512, 768, 896};
  int N = Ns[t], K = Ks[t], off = Off[t];
  for (int n = lane; n < N; n += 64) {
    vals[n] = wg[b * 960 + off + n];
    flags[n] = 0;
  }
  __syncthreads();
  for (int it = 0; it < K; ++it) {
    float bv = -1e30f;
    int bi = 0x7fffffff;
    for (int n = lane; n < N; n += 64) {
      float v = vals[n];
      if (v > bv || (v == bv && n < bi)) { bv = v; bi = n; }
    }
#pragma unroll
    for (int o = 1; o < 64; o <<= 1) {
      float ov = __shfl_xor(bv, o);
      int oi = __shfl_xor(bi, o);
      if (ov > bv || (ov == bv && oi < bi)) { bv = ov; bi = oi; }
    }
    if (lane == 0) { vals[bi] = -1e30f; flags[bi] = 1; }
    __syncthreads();
  }
  if (t == 0) {  // idx_qk: sorted ascending indices as floats
    if (lane == 0) {
      int pos = 0;
      for (int n = 0; n < 512; ++n)
        if (flags[n]) out[b * 64 + (pos++)] = (float)n;
    }
  } else if (t == 1) {  // idx_v
    if (lane == 0) {
      int pos = 0;
      for (int n = 0; n < 256; ++n)
        if (flags[n]) out[512 + b * 32 + (pos++)] = (float)n;
    }
  } else if (t == 2) {  // rel_Q and rel_K (identical)
    for (int n = lane; n < 128; n += 64) {
      float v = flags[n] ? wg[b * 960 + 768 + n] : 0.f;
      out[768 + b * 128 + n] = v;
      out[1792 + b * 128 + n] = v;
    }
  } else {  // val_w
    for (int n = lane; n < 64; n += 64) {
      float v = flags[n] ? wg[b * 960 + 896 + n] : 0.f;
      out[2816 + b * 64 + n] = v;
    }
  }
}

extern "C" void kernel_launch(void* const* d_in, const int* in_sizes, int n_in,
                              void* d_out, int out_size, void* d_ws, size_t ws_size,
                              hipStream_t stream) {
  const float* x   = (const float*)d_in[0];   // 8*4096*1024
  const float* imp = (const float*)d_in[1];   // 8*4096
  const float* pw  = (const float*)d_in[2];   // 64*1024
  const float* pb  = (const float*)d_in[3];   // 64
  const float* emb = (const float*)d_in[4];   // 1216*64
  float* out = (float*)d_out;                 // 3328 floats

  char* ws = (char*)d_ws;
  float* h    = (float*)(ws);                 // 32768*64  = 8 MiB
  float* embT = (float*)(ws + 8388608);       // 64*960    = 240 KiB
  float* wg   = (float*)(ws + 8634368);       // 8*960     = 30 KiB

  hipLaunchKernelGGL(k_norm, dim3(240), dim3(256), 0, stream, emb, embT, wg);
  hipLaunchKernelGGL(k_proj, dim3(512), dim3(256), 0, stream, x, pw, pb, h);
  hipLaunchKernelGGL(k_agg, dim3(1024), dim3(256), 0, stream, h, embT, imp, wg);
  hipLaunchKernelGGL(k_topk, dim3(32), dim3(64), 0, stream, wg, out);
}

// Round 2
// 383.200 us; speedup vs baseline: 1.5286x; 1.5286x over previous
//
#include <hip/hip_runtime.h>

// ---------------------------------------------------------------------------
// B=8, S=4096 (rows = 32768), D=1024, DS=64
// segments: qk 512 (tiles 0-31) | v 256 (32-47) | rel 128 (48-55) | val 64 (56-59)
// outputs (flat fp32): idx_qk 8x64 | idx_v 8x32 | rel_Q 8x128 | rel_K 8x128 | val_w 8x64
// Strategy: split-bf16 (hi+lo) MFMA 16x16x32 for both GEMMs; frags straight
// from global (cacheline-coalesced b128), no operand LDS, no barriers in hot loops.
// ---------------------------------------------------------------------------

typedef short short8 __attribute__((ext_vector_type(8)));   // 8 bf16 = 4 VGPR
typedef float f32x4 __attribute__((ext_vector_type(4)));

__device__ __forceinline__ unsigned short f32_to_bf16(float f) {
  unsigned u = __float_as_uint(f);
  u += 0x7FFF + ((u >> 16) & 1);  // RNE
  return (unsigned short)(u >> 16);
}
__device__ __forceinline__ float bf16_to_f32(unsigned short h) {
  return __uint_as_float(((unsigned)h) << 16);
}
__device__ __forceinline__ void split8(const float4& a0, const float4& a1,
                                       short8& hi, short8& lo) {
  float af[8] = {a0.x, a0.y, a0.z, a0.w, a1.x, a1.y, a1.z, a1.w};
#pragma unroll
  for (int j = 0; j < 8; ++j) {
    unsigned short h = f32_to_bf16(af[j]);
    hi[j] = (short)h;
    lo[j] = (short)f32_to_bf16(af[j] - bf16_to_f32(h));
  }
}
#define MFMA(a, b, c) __builtin_amdgcn_mfma_f32_16x16x32_bf16(a, b, c, 0, 0, 0)

// ---- k_prep: zero wg; split proj_w -> whi/wlo; normalize+split emb -> ehi/elo ----
__global__ __launch_bounds__(256) void k_prep(const float* __restrict__ pw,
                                              const float* __restrict__ emb,
                                              unsigned short* __restrict__ whi,
                                              unsigned short* __restrict__ wlo,
                                              unsigned short* __restrict__ ehi,
                                              unsigned short* __restrict__ elo,
                                              float* __restrict__ wg) {
  int tid = blockIdx.x * 256 + threadIdx.x;
  if (tid < 7680) wg[tid] = 0.f;
  for (int i = tid; i < 65536; i += gridDim.x * 256) {
    float v = pw[i];
    unsigned short h = f32_to_bf16(v);
    whi[i] = h;
    wlo[i] = f32_to_bf16(v - bf16_to_f32(h));
  }
  int wid = tid >> 6, lane = tid & 63;
  int nw = gridDim.x * 4;
  for (int n = wid; n < 960; n += nw) {
    float v = emb[n * 64 + lane];
    float s = v * v;
#pragma unroll
    for (int off = 1; off < 64; off <<= 1) s += __shfl_xor(s, off);
    float vn = v / sqrtf(s);
    unsigned short h = f32_to_bf16(vn);
    ehi[n * 64 + lane] = h;
    elo[n * 64 + lane] = f32_to_bf16(vn - bf16_to_f32(h));
  }
}

// ---- k_proj: h[32768][64] = x @ W^T + b via split-bf16 MFMA; h stored hi/lo bf16 ----
// grid 256 x 256thr; wave = 2 M-tiles (32 rows) x 4 N-tiles (64 cols); K = 1024.
__global__ __launch_bounds__(256) void k_proj(const float* __restrict__ x,
                                              const unsigned short* __restrict__ whi,
                                              const unsigned short* __restrict__ wlo,
                                              const float* __restrict__ pb,
                                              unsigned short* __restrict__ hhi,
                                              unsigned short* __restrict__ hlo) {
  int tid = threadIdx.x, w = tid >> 6, lane = tid & 63;
  int q = lane >> 4, c = lane & 15;
  int m0 = blockIdx.x * 128 + w * 32;  // wave's first row (2 M-tiles: m0, m0+16)

  f32x4 acc[2][4];
#pragma unroll
  for (int mt = 0; mt < 2; ++mt)
#pragma unroll
    for (int nt = 0; nt < 4; ++nt) acc[mt][nt] = (f32x4){0.f, 0.f, 0.f, 0.f};

  const float* ap0 = x + (size_t)(m0 + c) * 1024 + q * 8;
  const float* ap1 = x + (size_t)(m0 + 16 + c) * 1024 + q * 8;
  float4 a00 = *(const float4*)(ap0), a01 = *(const float4*)(ap0 + 4);
  float4 a10 = *(const float4*)(ap1), a11 = *(const float4*)(ap1 + 4);

  for (int ks = 0; ks < 32; ++ks) {
    float4 n00, n01, n10, n11;
    if (ks < 31) {  // prefetch next kstep's x (HBM) before compute
      n00 = *(const float4*)(ap0 + (ks + 1) * 32);
      n01 = *(const float4*)(ap0 + (ks + 1) * 32 + 4);
      n10 = *(const float4*)(ap1 + (ks + 1) * 32);
      n11 = *(const float4*)(ap1 + (ks + 1) * 32 + 4);
    }
    short8 ahi[2], alo[2];
    split8(a00, a01, ahi[0], alo[0]);
    split8(a10, a11, ahi[1], alo[1]);
#pragma unroll
    for (int nt = 0; nt < 4; ++nt) {
      size_t boff = (size_t)(nt * 16 + c) * 1024 + ks * 32 + q * 8;
      short8 bhi = *(const short8*)(whi + boff);
      short8 blo = *(const short8*)(wlo + boff);
#pragma unroll
      for (int mt = 0; mt < 2; ++mt) {
        acc[mt][nt] = MFMA(ahi[mt], bhi, acc[mt][nt]);
        acc[mt][nt] = MFMA(ahi[mt], blo, acc[mt][nt]);
        acc[mt][nt] = MFMA(alo[mt], bhi, acc[mt][nt]);
      }
    }
    a00 = n00; a01 = n01; a10 = n10; a11 = n11;
  }

  // epilogue: + bias, split to hi/lo bf16, store row-major [32768][64]
#pragma unroll
  for (int nt = 0; nt < 4; ++nt) {
    float bias = pb[nt * 16 + c];
#pragma unroll
    for (int mt = 0; mt < 2; ++mt) {
#pragma unroll
      for (int r = 0; r < 4; ++r) {
        float val = acc[mt][nt][r] + bias;            // C: row=(q*4+r), col=c
        int row = m0 + mt * 16 + q * 4 + r;
        unsigned short h = f32_to_bf16(val);
        hhi[(size_t)row * 64 + nt * 16 + c] = h;
        hlo[(size_t)row * 64 + nt * 16 + c] = f32_to_bf16(val - bf16_to_f32(h));
      }
    }
  }
}

// ---- k_agg: logits + segment softmax + importance-weighted agg, two-pass ----
// grid 512 x 256thr; block = 64 rows; wave strides N-tiles (nt = w + 4i, 15 tiles).
// A-frags (h hi/lo, all 4 M-tiles x 2 ksteps) persist in VGPRs across both passes.
__global__ __launch_bounds__(256) void k_agg(const unsigned short* __restrict__ hhi,
                                             const unsigned short* __restrict__ hlo,
                                             const unsigned short* __restrict__ ehi,
                                             const unsigned short* __restrict__ elo,
                                             const float* __restrict__ imp,
                                             float* __restrict__ wg) {
  __shared__ float zpart[4][64][4];  // [wave][row][seg]
  __shared__ float coefL[64][4];     // imp/Z per [row][seg]
  int tid = threadIdx.x, w = tid >> 6, lane = tid & 63;
  int q = lane >> 4, c = lane & 15;
  int row0 = blockIdx.x * 64;
  int b = row0 >> 12;

  short8 Ahi[4][2], Alo[4][2];
#pragma unroll
  for (int mt = 0; mt < 4; ++mt)
#pragma unroll
    for (int ks = 0; ks < 2; ++ks) {
      size_t base = (size_t)(row0 + mt * 16 + c) * 64 + ks * 32 + q * 8;
      Ahi[mt][ks] = *(const short8*)(hhi + base);
      Alo[mt][ks] = *(const short8*)(hlo + base);
    }

  // ---------------- pass 1: segment Z ----------------
  f32x4 zacc[4];
#pragma unroll
  for (int mt = 0; mt < 4; ++mt) zacc[mt] = (f32x4){0.f, 0.f, 0.f, 0.f};
  int cur_seg = 0;
  for (int i = 0; i < 15; ++i) {
    int nt = w + 4 * i;
    int s = (nt < 32) ? 0 : (nt < 48) ? 1 : (nt < 56) ? 2 : 3;
    if (s != cur_seg) {  // flush zacc for cur_seg
#pragma unroll
      for (int mt = 0; mt < 4; ++mt)
#pragma unroll
        for (int r = 0; r < 4; ++r) {
          float v = zacc[mt][r];
          v += __shfl_xor(v, 1); v += __shfl_xor(v, 2);
          v += __shfl_xor(v, 4); v += __shfl_xor(v, 8);
          if (c == 0) zpart[w][mt * 16 + q * 4 + r][cur_seg] = v;
          zacc[mt][r] = 0.f;
        }
      cur_seg = s;
    }
    size_t eb = (size_t)(nt * 16 + c) * 64 + q * 8;
    short8 bhi0 = *(const short8*)(ehi + eb), bhi1 = *(const short8*)(ehi + eb + 32);
    short8 blo0 = *(const short8*)(elo + eb), blo1 = *(const short8*)(elo + eb + 32);
#pragma unroll
    for (int mt = 0; mt < 4; ++mt) {
      f32x4 l = (f32x4){0.f, 0.f, 0.f, 0.f};
      l = MFMA(Ahi[mt][0], bhi0, l); l = MFMA(Ahi[mt][1], bhi1, l);
      l = MFMA(Ahi[mt][0], blo0, l); l = MFMA(Ahi[mt][1], blo1, l);
      l = MFMA(Alo[mt][0], bhi0, l); l = MFMA(Alo[mt][1], bhi1, l);
#pragma unroll
      for (int r = 0; r < 4; ++r) zacc[mt][r] += __expf(l[r]);
    }
  }
#pragma unroll
  for (int mt = 0; mt < 4; ++mt)  // final flush (val segment)
#pragma unroll
    for (int r = 0; r < 4; ++r) {
      float v = zacc[mt][r];
      v += __shfl_xor(v, 1); v += __shfl_xor(v, 2);
      v += __shfl_xor(v, 4); v += __shfl_xor(v, 8);
      if (c == 0) zpart[w][mt * 16 + q * 4 + r][cur_seg] = v;
    }
  __syncthreads();
  {  // combine: 256 threads = 64 rows x 4 segs
    int row = tid & 63, sg = tid >> 6;
    float Z = zpart[0][row][sg] + zpart[1][row][sg] + zpart[2][row][sg] + zpart[3][row][sg];
    coefL[row][sg] = imp[row0 + row] / Z;
  }
  __syncthreads();

  // ---------------- pass 2: weighted exp accumulation ----------------
  f32x4 cf[4];
  int cs2 = -1;
  for (int i = 0; i < 15; ++i) {
    int nt = w + 4 * i;
    int s = (nt < 32) ? 0 : (nt < 48) ? 1 : (nt < 56) ? 2 : 3;
    if (s != cs2) {
#pragma unroll
      for (int mt = 0; mt < 4; ++mt)
#pragma unroll
        for (int r = 0; r < 4; ++r) cf[mt][r] = coefL[mt * 16 + q * 4 + r][s];
      cs2 = s;
    }
    size_t eb = (size_t)(nt * 16 + c) * 64 + q * 8;
    short8 bhi0 = *(const short8*)(ehi + eb), bhi1 = *(const short8*)(ehi + eb + 32);
    short8 blo0 = *(const short8*)(elo + eb), blo1 = *(const short8*)(elo + eb + 32);
    float wsum = 0.f;
#pragma unroll
    for (int mt = 0; mt < 4; ++mt) {
      f32x4 l = (f32x4){0.f, 0.f, 0.f, 0.f};
      l = MFMA(Ahi[mt][0], bhi0, l); l = MFMA(Ahi[mt][1], bhi1, l);
      l = MFMA(Ahi[mt][0], blo0, l); l = MFMA(Ahi[mt][1], blo1, l);
      l = MFMA(Alo[mt][0], bhi0, l); l = MFMA(Alo[mt][1], bhi1, l);
#pragma unroll
      for (int r = 0; r < 4; ++r) wsum = fmaf(__expf(l[r]), cf[mt][r], wsum);
    }
    wsum += __shfl_xor(wsum, 16);
    wsum += __shfl_xor(wsum, 32);  // lanes sharing col c now hold full 64-row sum
    if (lane < 16) atomicAdd(&wg[b * 960 + nt * 16 + c], wsum);
  }
}

// ---- k_topk: per (b, type) iterative top-k extraction + output emission ----
__global__ __launch_bounds__(64) void k_topk(const float* __restrict__ wg,
                                             float* __restrict__ out) {
  __shared__ float vals[512];
  __shared__ int flags[512];
  int blk = blockIdx.x;
  int b = blk >> 2, t = blk & 3;
  int lane = threadIdx.x;
  const int Ns[4] = {512, 256, 128, 64};
  const int Ks[4] = {64, 32, 16, 3};
  const int Off[4] = {0, 512, 768, 896};
  int N = Ns[t], K = Ks[t], off = Off[t];
  for (int n = lane; n < N; n += 64) {
    vals[n] = wg[b * 960 + off + n];
    flags[n] = 0;
  }
  __syncthreads();
  for (int it = 0; it < K; ++it) {
    float bv = -1e30f;
    int bi = 0x7fffffff;
    for (int n = lane; n < N; n += 64) {
      float v = vals[n];
      if (v > bv || (v == bv && n < bi)) { bv = v; bi = n; }
    }
#pragma unroll
    for (int o = 1; o < 64; o <<= 1) {
      float ov = __shfl_xor(bv, o);
      int oi = __shfl_xor(bi, o);
      if (ov > bv || (ov == bv && oi < bi)) { bv = ov; bi = oi; }
    }
    if (lane == 0) { vals[bi] = -1e30f; flags[bi] = 1; }
    __syncthreads();
  }
  if (t == 0) {
    if (lane == 0) {
      int pos = 0;
      for (int n = 0; n < 512; ++n)
        if (flags[n]) out[b * 64 + (pos++)] = (float)n;
    }
  } else if (t == 1) {
    if (lane == 0) {
      int pos = 0;
      for (int n = 0; n < 256; ++n)
        if (flags[n]) out[512 + b * 32 + (pos++)] = (float)n;
    }
  } else if (t == 2) {
    for (int n = lane; n < 128; n += 64) {
      float v = flags[n] ? wg[b * 960 + 768 + n] : 0.f;
      out[768 + b * 128 + n] = v;
      out[1792 + b * 128 + n] = v;
    }
  } else {
    for (int n = lane; n < 64; n += 64) {
      float v = flags[n] ? wg[b * 960 + 896 + n] : 0.f;
      out[2816 + b * 64 + n] = v;
    }
  }
}

extern "C" void kernel_launch(void* const* d_in, const int* in_sizes, int n_in,
                              void* d_out, int out_size, void* d_ws, size_t ws_size,
                              hipStream_t stream) {
  const float* x   = (const float*)d_in[0];   // 8*4096*1024
  const float* imp = (const float*)d_in[1];   // 8*4096
  const float* pw  = (const float*)d_in[2];   // 64*1024
  const float* pb  = (const float*)d_in[3];   // 64
  const float* emb = (const float*)d_in[4];   // 1216*64
  float* out = (float*)d_out;                 // 3328 floats

  char* ws = (char*)d_ws;
  unsigned short* hhi = (unsigned short*)(ws);             // 32768*64*2 = 4 MiB
  unsigned short* hlo = (unsigned short*)(ws + 4194304);   // 4 MiB
  unsigned short* whi = (unsigned short*)(ws + 8388608);   // 128 KiB
  unsigned short* wlo = (unsigned short*)(ws + 8519680);   // 128 KiB
  unsigned short* ehi = (unsigned short*)(ws + 8650752);   // 120 KiB
  unsigned short* elo = (unsigned short*)(ws + 8773632);   // 120 KiB
  float*          wg  = (float*)(ws + 8896512);            // 30 KiB

  hipLaunchKernelGGL(k_prep, dim3(64), dim3(256), 0, stream, pw, emb, whi, wlo, ehi, elo, wg);
  hipLaunchKernelGGL(k_proj, dim3(256), dim3(256), 0, stream, x, whi, wlo, pb, hhi, hlo);
  hipLaunchKernelGGL(k_agg,  dim3(512), dim3(256), 0, stream, hhi, hlo, ehi, elo, imp, wg);
  hipLaunchKernelGGL(k_topk, dim3(32), dim3(64), 0, stream, wg, out);
}

// Round 3
// 350.721 us; speedup vs baseline: 1.6701x; 1.0926x over previous
//
#include <hip/hip_runtime.h>

// ---------------------------------------------------------------------------
// B=8, S=4096 (rows = 32768), D=1024, DS=64
// segments: qk 512 (tiles 0-31) | v 256 (32-47) | rel 128 (48-55) | val 64 (56-59)
// outputs (flat fp32): idx_qk 8x64 | idx_v 8x32 | rel_Q 8x128 | rel_K 8x128 | val_w 8x64
// Split-bf16 (hi+lo, 3-term) MFMA 16x16x32 for both GEMMs, frags straight from
// global/L1. R3: occupancy fixes (1024-block proj/agg) + parallel rank-based topk.
// ---------------------------------------------------------------------------

typedef short short8 __attribute__((ext_vector_type(8)));   // 8 bf16 = 4 VGPR
typedef float f32x4 __attribute__((ext_vector_type(4)));

__device__ __forceinline__ unsigned short f32_to_bf16(float f) {
  unsigned u = __float_as_uint(f);
  u += 0x7FFF + ((u >> 16) & 1);  // RNE
  return (unsigned short)(u >> 16);
}
__device__ __forceinline__ float bf16_to_f32(unsigned short h) {
  return __uint_as_float(((unsigned)h) << 16);
}
__device__ __forceinline__ void split8(const float4& a0, const float4& a1,
                                       short8& hi, short8& lo) {
  float af[8] = {a0.x, a0.y, a0.z, a0.w, a1.x, a1.y, a1.z, a1.w};
#pragma unroll
  for (int j = 0; j < 8; ++j) {
    unsigned short h = f32_to_bf16(af[j]);
    hi[j] = (short)h;
    lo[j] = (short)f32_to_bf16(af[j] - bf16_to_f32(h));
  }
}
#define MFMA(a, b, c) __builtin_amdgcn_mfma_f32_16x16x32_bf16(a, b, c, 0, 0, 0)

// ---- k_prep: zero wg; split proj_w -> whi/wlo; normalize+split emb -> ehi/elo ----
__global__ __launch_bounds__(256) void k_prep(const float* __restrict__ pw,
                                              const float* __restrict__ emb,
                                              unsigned short* __restrict__ whi,
                                              unsigned short* __restrict__ wlo,
                                              unsigned short* __restrict__ ehi,
                                              unsigned short* __restrict__ elo,
                                              float* __restrict__ wg) {
  int tid = blockIdx.x * 256 + threadIdx.x;
  if (tid < 7680) wg[tid] = 0.f;
  for (int i = tid; i < 65536; i += gridDim.x * 256) {
    float v = pw[i];
    unsigned short h = f32_to_bf16(v);
    whi[i] = h;
    wlo[i] = f32_to_bf16(v - bf16_to_f32(h));
  }
  int wid = tid >> 6, lane = tid & 63;
  int nw = gridDim.x * 4;
  for (int n = wid; n < 960; n += nw) {
    float v = emb[n * 64 + lane];
    float s = v * v;
#pragma unroll
    for (int off = 1; off < 64; off <<= 1) s += __shfl_xor(s, off);
    float vn = v / sqrtf(s);
    unsigned short h = f32_to_bf16(vn);
    ehi[n * 64 + lane] = h;
    elo[n * 64 + lane] = f32_to_bf16(vn - bf16_to_f32(h));
  }
}

// ---- k_proj: h = x @ W^T + b, split-bf16 MFMA; h stored hi/lo bf16 ----
// grid 1024 x 256thr; block = 32 rows; wave w owns N-tile nt=w (16 cols).
// x rows shared by the block's 4 waves (L1 hits); 4 blocks/CU -> 4 waves/SIMD.
__global__ __launch_bounds__(256) void k_proj(const float* __restrict__ x,
                                              const unsigned short* __restrict__ whi,
                                              const unsigned short* __restrict__ wlo,
                                              const float* __restrict__ pb,
                                              unsigned short* __restrict__ hhi,
                                              unsigned short* __restrict__ hlo) {
  int tid = threadIdx.x, w = tid >> 6, lane = tid & 63;
  int q = lane >> 4, c = lane & 15;
  int m0 = blockIdx.x * 32;
  int nt = w;

  f32x4 acc[2];
  acc[0] = (f32x4){0.f, 0.f, 0.f, 0.f};
  acc[1] = (f32x4){0.f, 0.f, 0.f, 0.f};

  const float* ap0 = x + (size_t)(m0 + c) * 1024 + q * 8;
  const float* ap1 = x + (size_t)(m0 + 16 + c) * 1024 + q * 8;
  float4 a00 = *(const float4*)(ap0), a01 = *(const float4*)(ap0 + 4);
  float4 a10 = *(const float4*)(ap1), a11 = *(const float4*)(ap1 + 4);

  for (int ks = 0; ks < 32; ++ks) {
    float4 n00, n01, n10, n11;
    if (ks < 31) {  // prefetch next kstep's x before compute
      n00 = *(const float4*)(ap0 + (ks + 1) * 32);
      n01 = *(const float4*)(ap0 + (ks + 1) * 32 + 4);
      n10 = *(const float4*)(ap1 + (ks + 1) * 32);
      n11 = *(const float4*)(ap1 + (ks + 1) * 32 + 4);
    }
    size_t boff = (size_t)(nt * 16 + c) * 1024 + ks * 32 + q * 8;
    short8 bhi = *(const short8*)(whi + boff);
    short8 blo = *(const short8*)(wlo + boff);
    short8 ahi[2], alo[2];
    split8(a00, a01, ahi[0], alo[0]);
    split8(a10, a11, ahi[1], alo[1]);
#pragma unroll
    for (int mt = 0; mt < 2; ++mt) {
      acc[mt] = MFMA(ahi[mt], bhi, acc[mt]);
      acc[mt] = MFMA(ahi[mt], blo, acc[mt]);
      acc[mt] = MFMA(alo[mt], bhi, acc[mt]);
    }
    if (ks < 31) { a00 = n00; a01 = n01; a10 = n10; a11 = n11; }
  }

  float bias = pb[nt * 16 + c];
#pragma unroll
  for (int mt = 0; mt < 2; ++mt) {
#pragma unroll
    for (int r = 0; r < 4; ++r) {
      float val = acc[mt][r] + bias;  // C: row=(q*4+r), col=c
      int row = m0 + mt * 16 + q * 4 + r;
      unsigned short h = f32_to_bf16(val);
      hhi[(size_t)row * 64 + nt * 16 + c] = h;
      hlo[(size_t)row * 64 + nt * 16 + c] = f32_to_bf16(val - bf16_to_f32(h));
    }
  }
}

// ---- k_agg: logits + segment softmax + importance-weighted agg, two-pass ----
// grid 1024 x 256thr; block = 32 rows (2 M-tiles); wave strides N-tiles (nt=w+4i).
// A-frags (h hi/lo) persist in VGPRs across both passes.
__global__ __launch_bounds__(256) void k_agg(const unsigned short* __restrict__ hhi,
                                             const unsigned short* __restrict__ hlo,
                                             const unsigned short* __restrict__ ehi,
                                             const unsigned short* __restrict__ elo,
                                             const float* __restrict__ imp,
                                             float* __restrict__ wg) {
  __shared__ float zpart[4][32][4];  // [wave][row][seg]
  __shared__ float coefL[32][4];     // imp/Z per [row][seg]
  int tid = threadIdx.x, w = tid >> 6, lane = tid & 63;
  int q = lane >> 4, c = lane & 15;
  int row0 = blockIdx.x * 32;
  int b = row0 >> 12;

  short8 Ahi[2][2], Alo[2][2];
#pragma unroll
  for (int mt = 0; mt < 2; ++mt)
#pragma unroll
    for (int ks = 0; ks < 2; ++ks) {
      size_t base = (size_t)(row0 + mt * 16 + c) * 64 + ks * 32 + q * 8;
      Ahi[mt][ks] = *(const short8*)(hhi + base);
      Alo[mt][ks] = *(const short8*)(hlo + base);
    }

  // ---------------- pass 1: segment Z ----------------
  f32x4 zacc[2];
  zacc[0] = (f32x4){0.f, 0.f, 0.f, 0.f};
  zacc[1] = (f32x4){0.f, 0.f, 0.f, 0.f};
  int cur_seg = 0;
  for (int i = 0; i < 15; ++i) {
    int nt = w + 4 * i;
    int s = (nt < 32) ? 0 : (nt < 48) ? 1 : (nt < 56) ? 2 : 3;
    if (s != cur_seg) {  // flush zacc for cur_seg
#pragma unroll
      for (int mt = 0; mt < 2; ++mt)
#pragma unroll
        for (int r = 0; r < 4; ++r) {
          float v = zacc[mt][r];
          v += __shfl_xor(v, 1); v += __shfl_xor(v, 2);
          v += __shfl_xor(v, 4); v += __shfl_xor(v, 8);
          if (c == 0) zpart[w][mt * 16 + q * 4 + r][cur_seg] = v;
          zacc[mt][r] = 0.f;
        }
      cur_seg = s;
    }
    size_t eb = (size_t)(nt * 16 + c) * 64 + q * 8;
    short8 bhi0 = *(const short8*)(ehi + eb), bhi1 = *(const short8*)(ehi + eb + 32);
    short8 blo0 = *(const short8*)(elo + eb), blo1 = *(const short8*)(elo + eb + 32);
#pragma unroll
    for (int mt = 0; mt < 2; ++mt) {
      f32x4 l = (f32x4){0.f, 0.f, 0.f, 0.f};
      l = MFMA(Ahi[mt][0], bhi0, l); l = MFMA(Ahi[mt][1], bhi1, l);
      l = MFMA(Ahi[mt][0], blo0, l); l = MFMA(Ahi[mt][1], blo1, l);
      l = MFMA(Alo[mt][0], bhi0, l); l = MFMA(Alo[mt][1], bhi1, l);
#pragma unroll
      for (int r = 0; r < 4; ++r) zacc[mt][r] += __expf(l[r]);
    }
  }
#pragma unroll
  for (int mt = 0; mt < 2; ++mt)  // final flush (val segment)
#pragma unroll
    for (int r = 0; r < 4; ++r) {
      float v = zacc[mt][r];
      v += __shfl_xor(v, 1); v += __shfl_xor(v, 2);
      v += __shfl_xor(v, 4); v += __shfl_xor(v, 8);
      if (c == 0) zpart[w][mt * 16 + q * 4 + r][cur_seg] = v;
    }
  __syncthreads();
  if (tid < 128) {  // combine: 128 threads = 32 rows x 4 segs
    int row = tid & 31, sg = tid >> 5;
    float Z = zpart[0][row][sg] + zpart[1][row][sg] + zpart[2][row][sg] + zpart[3][row][sg];
    coefL[row][sg] = imp[row0 + row] / Z;
  }
  __syncthreads();

  // ---------------- pass 2: weighted exp accumulation ----------------
  f32x4 cf[2];
  int cs2 = -1;
  for (int i = 0; i < 15; ++i) {
    int nt = w + 4 * i;
    int s = (nt < 32) ? 0 : (nt < 48) ? 1 : (nt < 56) ? 2 : 3;
    if (s != cs2) {
#pragma unroll
      for (int mt = 0; mt < 2; ++mt)
#pragma unroll
        for (int r = 0; r < 4; ++r) cf[mt][r] = coefL[mt * 16 + q * 4 + r][s];
      cs2 = s;
    }
    size_t eb = (size_t)(nt * 16 + c) * 64 + q * 8;
    short8 bhi0 = *(const short8*)(ehi + eb), bhi1 = *(const short8*)(ehi + eb + 32);
    short8 blo0 = *(const short8*)(elo + eb), blo1 = *(const short8*)(elo + eb + 32);
    float wsum = 0.f;
#pragma unroll
    for (int mt = 0; mt < 2; ++mt) {
      f32x4 l = (f32x4){0.f, 0.f, 0.f, 0.f};
      l = MFMA(Ahi[mt][0], bhi0, l); l = MFMA(Ahi[mt][1], bhi1, l);
      l = MFMA(Ahi[mt][0], blo0, l); l = MFMA(Ahi[mt][1], blo1, l);
      l = MFMA(Alo[mt][0], bhi0, l); l = MFMA(Alo[mt][1], bhi1, l);
#pragma unroll
      for (int r = 0; r < 4; ++r) wsum = fmaf(__expf(l[r]), cf[mt][r], wsum);
    }
    wsum += __shfl_xor(wsum, 16);
    wsum += __shfl_xor(wsum, 32);  // lanes sharing col c now hold all 32 rows' sum
    if (lane < 16) atomicAdd(&wg[b * 960 + nt * 16 + c], wsum);
  }
}

// ---- k_topk: parallel rank-based selection + ballot emission ----
// 32 blocks x 256thr, block = (b, type). n in top-K iff
// #{m : v[m]>v[n] or (v[m]==v[n] and m<n)} < K  (matches lax.top_k tie-break).
__global__ __launch_bounds__(256) void k_topk(const float* __restrict__ wg,
                                              float* __restrict__ out) {
  __shared__ float vals[512];
  __shared__ int flags[512];
  int blk = blockIdx.x;
  int b = blk >> 2, t = blk & 3;
  int tid = threadIdx.x;
  const int Ns[4] = {512, 256, 128, 64};
  const int Ks[4] = {64, 32, 16, 3};
  const int Off[4] = {0, 512, 768, 896};
  int N = Ns[t], K = Ks[t], off = Off[t];
  for (int n = tid; n < N; n += 256) vals[n] = wg[b * 960 + off + n];
  __syncthreads();
  for (int n = tid; n < N; n += 256) {
    float v = vals[n];
    int rank = 0;
    for (int m = 0; m < N; ++m) {  // LDS broadcast reads, fully parallel
      float u = vals[m];
      rank += (u > v || (u == v && m < n)) ? 1 : 0;
    }
    flags[n] = (rank < K) ? 1 : 0;
  }
  __syncthreads();
  if (t <= 1) {  // index outputs: sorted ascending via ballot prefix (wave 0)
    if (tid < 64) {
      int base = 0;
      for (int ch = 0; ch < N; ch += 64) {
        int n = ch + tid;
        int f = flags[n];
        unsigned long long mask = __ballot(f);
        if (f) {
          int pos = base + __popcll(mask & ((1ull << tid) - 1ull));
          if (t == 0) out[b * 64 + pos] = (float)n;
          else out[512 + b * 32 + pos] = (float)n;
        }
        base += __popcll(mask);
      }
    }
  } else if (t == 2) {  // rel_Q and rel_K (identical sparse vectors)
    for (int n = tid; n < 128; n += 256) {
      float v = flags[n] ? vals[n] : 0.f;
      out[768 + b * 128 + n] = v;
      out[1792 + b * 128 + n] = v;
    }
  } else {  // val_w
    for (int n = tid; n < 64; n += 256) {
      float v = flags[n] ? vals[n] : 0.f;
      out[2816 + b * 64 + n] = v;
    }
  }
}

extern "C" void kernel_launch(void* const* d_in, const int* in_sizes, int n_in,
                              void* d_out, int out_size, void* d_ws, size_t ws_size,
                              hipStream_t stream) {
  const float* x   = (const float*)d_in[0];   // 8*4096*1024
  const float* imp = (const float*)d_in[1];   // 8*4096
  const float* pw  = (const float*)d_in[2];   // 64*1024
  const float* pb  = (const float*)d_in[3];   // 64
  const float* emb = (const float*)d_in[4];   // 1216*64
  float* out = (float*)d_out;                 // 3328 floats

  char* ws = (char*)d_ws;
  unsigned short* hhi = (unsigned short*)(ws);             // 4 MiB
  unsigned short* hlo = (unsigned short*)(ws + 4194304);   // 4 MiB
  unsigned short* whi = (unsigned short*)(ws + 8388608);   // 128 KiB
  unsigned short* wlo = (unsigned short*)(ws + 8519680);   // 128 KiB
  unsigned short* ehi = (unsigned short*)(ws + 8650752);   // 120 KiB
  unsigned short* elo = (unsigned short*)(ws + 8773632);   // 120 KiB
  float*          wg  = (float*)(ws + 8896512);            // 30 KiB

  hipLaunchKernelGGL(k_prep, dim3(64), dim3(256), 0, stream, pw, emb, whi, wlo, ehi, elo, wg);
  hipLaunchKernelGGL(k_proj, dim3(1024), dim3(256), 0, stream, x, whi, wlo, pb, hhi, hlo);
  hipLaunchKernelGGL(k_agg,  dim3(1024), dim3(256), 0, stream, hhi, hlo, ehi, elo, imp, wg);
  hipLaunchKernelGGL(k_topk, dim3(32), dim3(256), 0, stream, wg, out);
}